// Round 4
// baseline (337.781 us; speedup 1.0000x reference)
//
#include <hip/hip_runtime.h>

#define EMB 300
#define HID 10
#define BATCH 256
#define SEQ 512
#define ROWS (BATCH * SEQ)    // 131072
#define G3 (3 * HID)          // 30
#define KT 10                 // k-tiles of 32 (tile 9 offset 268, masked x-frag)
#define XP 36                 // padded LDS row stride (floats): 16B-aligned
#define PFD 8                 // scan prefetch depth (global gi reads)

#define NLOG2E 1.4426950408889634f   // log2(e)
#define TLOG2E 2.8853900817779268f   // 2*log2(e)

typedef __attribute__((ext_vector_type(8))) short short8;   // 8 bf16 = 4 VGPRs
typedef __attribute__((ext_vector_type(4))) float f32x4;    // MFMA C/D

__device__ __forceinline__ float fsig(float x) {
    float e = __builtin_amdgcn_exp2f(-NLOG2E * x);
    return __builtin_amdgcn_rcpf(1.0f + e);
}
__device__ __forceinline__ float ftanh(float x) {
    float e = __builtin_amdgcn_exp2f(TLOG2E * x);
    return fmaf(-2.0f, __builtin_amdgcn_rcpf(1.0f + e), 1.0f);
}
__device__ __forceinline__ float rdlane(float v, int lane) {
    return __int_as_float(__builtin_amdgcn_readlane(__float_as_int(v), lane));
}
__device__ __forceinline__ short bf16_hi(float f) {
    return (short)(__float_as_uint(f) >> 16);
}
__device__ __forceinline__ float bf16_tof(short h) {
    return __uint_as_float(((unsigned)(unsigned short)h) << 16);
}

// ---------------------------------------------------------------------------
// Kernel 1: gi[row][g] via split-bf16 MFMA. v8: k_prep folded in — each lane
// loads its own 2-gate weight fragment from w_ih (36 KB, L1/L2-hot across
// 2048 blocks) and splits to bf16 hi/lo in-kernel (~50 VALU/tile, ~2 us
// chip-wide, under the 25 us BW floor). Tile-9 dead lanes (ki<20) are masked
// on the X fragment (products identically zero, same numerics as the old
// masked weights). Gates 30/31 clamp their load row; their garbage lands in
// gi cols 30/31 which the scan never reads. x path: v7's 1-deep register
// prefetch + double-buffered LDS, one barrier per tile.
// ---------------------------------------------------------------------------
__global__ __launch_bounds__(256) void k_gi(const float* __restrict__ x,
                                            const float* __restrict__ w_ih,
                                            const float* __restrict__ b_ih,
                                            const float* __restrict__ b_hh,
                                            float* __restrict__ gi) {
    __shared__ float xs[2 * 64 * XP];             // 18432 B, double-buffered
    const int t    = threadIdx.x;
    const int wave = t >> 6, lane = t & 63;
    const int m = lane & 15, q = lane >> 4;
    const int base = blockIdx.x * 64;             // first of 64 rows
    const int rloc = wave * 16 + m;               // this lane's fragment row

    // gates 0..15 are all r/z -> fold b_hh in; gates 20..29 (n) keep b_hh
    // separate (scaled by r in the cell). g1 in {30,31} -> clamped row, col
    // unread downstream.
    const int g1  = 16 + m;
    const int g1c = (g1 < G3) ? g1 : G3 - 1;
    const float bias0 = b_ih[m] + b_hh[m];
    const float bias1 = (g1 < G3) ? (b_ih[g1] + ((g1 < 20) ? b_hh[g1] : 0.0f))
                                  : 0.0f;
    f32x4 acc0 = {bias0, bias0, bias0, bias0};
    f32x4 acc1 = {bias1, bias1, bias1, bias1};

    const int srow  = t >> 3;                     // staging: 8 thr per row
    const int spiece = (t & 7) * 4;
    const float* __restrict__ xg0 = x + (size_t)(base + srow) * EMB + spiece;
    const float* __restrict__ xg1 = x + (size_t)(base + 32 + srow) * EMB + spiece;
    float* __restrict__ ss = xs + srow * XP + spiece;   // + parity*(64*XP)

    const float* __restrict__ w0 = w_ih + (size_t)m   * EMB;
    const float* __restrict__ w1 = w_ih + (size_t)g1c * EMB;

    // prologue: issue tiles 0 and 1 together, then store tile 0 into buf0
    float4 ra0 = *(const float4*)(xg0);           // tile 0 (k0 = 0)
    float4 rb0 = *(const float4*)(xg1);
    float4 ra  = *(const float4*)(xg0 + 32);      // tile 1 (k0 = 32)
    float4 rb  = *(const float4*)(xg1 + 32);
    *(float4*)(ss)           = ra0;
    *(float4*)(ss + 32 * XP) = rb0;

#pragma unroll
    for (int kt = 0; kt < KT; kt++) {
        __syncthreads();  // buf[kt&1] complete; prev readers of buf[kt&1^1] done
        if (kt + 1 < KT) {
            float* d = ss + ((kt + 1) & 1) * (64 * XP);
            *(float4*)(d)           = ra;         // store tile kt+1
            *(float4*)(d + 32 * XP) = rb;
            if (kt + 2 < KT) {                    // issue tile kt+2
                const int k2 = (kt + 2 < 9) ? (kt + 2) * 32 : 268;
                ra = *(const float4*)(xg0 + k2);
                rb = *(const float4*)(xg1 + k2);
            }
        }

        // weight fragment for this tile (in-kernel split-bf16)
        const int kb = ((kt < 9) ? kt * 32 : 268) + q * 8;   // in-row, never OOB
        const float4 wa0 = *(const float4*)(w0 + kb);
        const float4 wb0 = *(const float4*)(w0 + kb + 4);
        const float4 wa1 = *(const float4*)(w1 + kb);
        const float4 wb1 = *(const float4*)(w1 + kb + 4);

        const float* fp = xs + (kt & 1) * (64 * XP) + rloc * XP + q * 8;
        const float4 xa = *(const float4*)fp;
        const float4 xb = *(const float4*)(fp + 4);
        float av[8] = {xa.x, xa.y, xa.z, xa.w, xb.x, xb.y, xb.z, xb.w};
        if (kt == 9) {                            // mask x elems with ki<20
#pragma unroll
            for (int j = 0; j < 8; j++)
                if (q * 8 + j < 20) av[j] = 0.0f; // tile9 covers k=268..299;
        }                                         // ki<20 already in tile 8

        float wv0[8] = {wa0.x, wa0.y, wa0.z, wa0.w, wb0.x, wb0.y, wb0.z, wb0.w};
        float wv1[8] = {wa1.x, wa1.y, wa1.z, wa1.w, wb1.x, wb1.y, wb1.z, wb1.w};

        short8 ah, al, bh0, bl0, bh1, bl1;
#pragma unroll
        for (int j = 0; j < 8; j++) {
            short hi;
            hi = bf16_hi(av[j]);  ah[j] = hi;  al[j] = bf16_hi(av[j] - bf16_tof(hi));
            hi = bf16_hi(wv0[j]); bh0[j] = hi; bl0[j] = bf16_hi(wv0[j] - bf16_tof(hi));
            hi = bf16_hi(wv1[j]); bh1[j] = hi; bl1[j] = bf16_hi(wv1[j] - bf16_tof(hi));
        }

        acc0 = __builtin_amdgcn_mfma_f32_16x16x32_bf16(ah, bh0, acc0, 0, 0, 0);
        acc0 = __builtin_amdgcn_mfma_f32_16x16x32_bf16(al, bh0, acc0, 0, 0, 0);
        acc0 = __builtin_amdgcn_mfma_f32_16x16x32_bf16(ah, bl0, acc0, 0, 0, 0);
        acc1 = __builtin_amdgcn_mfma_f32_16x16x32_bf16(ah, bh1, acc1, 0, 0, 0);
        acc1 = __builtin_amdgcn_mfma_f32_16x16x32_bf16(al, bh1, acc1, 0, 0, 0);
        acc1 = __builtin_amdgcn_mfma_f32_16x16x32_bf16(ah, bl1, acc1, 0, 0, 0);
    }
    // pre-scale for the scan's exp2-direct gates:
    //   cols 0..19 (r,z): * -log2(e);  cols 20..29 (n): * 2*log2(e)
    const float sc0 = -NLOG2E;                    // cols m=0..15 are all r/z
    const float sc1 = (m < 4) ? -NLOG2E : TLOG2E; // cols 16..19 z, 20..29 n
#pragma unroll
    for (int r = 0; r < 4; r++) {
        const size_t row = (size_t)(base + wave * 16 + q * 4 + r);
        gi[row * 32 + m]      = acc0[r] * sc0;
        gi[row * 32 + 16 + m] = acc1[r] * sc1;
    }
}

// ---------------------------------------------------------------------------
// Kernel 2: inline backward single-step + forward scan. v8: NO LDS staging —
// gi is read straight from global with an 8-step register prefetch (L2-warm,
// ~24 outstanding dwords; 8 x ~180cy chain covers HBM latency). This also
// decouples the prefetch (vmcnt) from the ds_swizzle broadcasts (lgkmcnt):
// previously every per-step lgkmcnt(0) for the broadcast drained the LDS
// prefetch reads too. Dots use 3 accumulators (serial chain 4 FMAs).
// ---------------------------------------------------------------------------
__global__ __launch_bounds__(256) void k_scan(const float* __restrict__ gi,
                                              const float* __restrict__ w_hh,
                                              const float* __restrict__ b_hh,
                                              const float* __restrict__ x,
                                              const float* __restrict__ w_ih_b,
                                              const float* __restrict__ b_ih_b,
                                              const float* __restrict__ b_hh_b,
                                              const float* __restrict__ w_lin,
                                              const float* __restrict__ b_lin,
                                              float* __restrict__ out) {
    __shared__ float gsum[G3];
    __shared__ float hbs[HID];
    const int b = blockIdx.x;
    const int t = threadIdx.x;

    // backward direction: one GRU step on x[:,511], h0=0
    if (t < G3 * 8) {
        const int g = t >> 3, jj = t & 7;
        const float* __restrict__ xrow = x + ((size_t)b * SEQ + (SEQ - 1)) * EMB;
        float acc = 0.0f;
#pragma unroll
        for (int i = 0; i < 10; ++i) {
            const int k = jj * 4 + i * 32;
            if (k < EMB) {
                const float4 wv = *(const float4*)(w_ih_b + (size_t)g * EMB + k);
                const float4 xv = *(const float4*)(xrow + k);
                acc = fmaf(xv.x, wv.x, acc);
                acc = fmaf(xv.y, wv.y, acc);
                acc = fmaf(xv.z, wv.z, acc);
                acc = fmaf(xv.w, wv.w, acc);
            }
        }
        acc += __shfl_down(acc, 4, 8);
        acc += __shfl_down(acc, 2, 8);
        acc += __shfl_down(acc, 1, 8);
        if (jj == 0) gsum[g] = acc + b_ih_b[g];
    }
    __syncthreads();
    if (t < HID) {
        const float r = fsig(gsum[t] + b_hh_b[t]);
        const float z = fsig(gsum[HID + t] + b_hh_b[HID + t]);
        const float n = ftanh(fmaf(r, b_hh_b[2 * HID + t], gsum[2 * HID + t]));
        hbs[t] = (1.0f - z) * n;
    }
    __syncthreads();
    if (t >= 64) return;

    // ---- forward recurrence, 1 wave, gi from global, constants folded
    const int j = t;
    const int jc = (j < HID) ? j : HID - 1;
    const float* __restrict__ gb = gi + (size_t)b * SEQ * 32;

    float wr[HID], wz[HID], wn[HID];
#pragma unroll
    for (int k = 0; k < HID; k++) {
        wr[k] = -NLOG2E * w_hh[jc * HID + k];
        wz[k] = -NLOG2E * w_hh[(HID + jc) * HID + k];
        wn[k] =  TLOG2E * w_hh[(2 * HID + jc) * HID + k];
    }
    const float bn  = TLOG2E * b_hh[2 * HID + jc];  // r/z b_hh folded into gi
    const float hbv = hbs[jc];

    float pr[PFD], pz[PFD], pn[PFD];
#pragma unroll
    for (int d = 0; d < PFD; d++) {
        pr[d] = gb[d * 32 + jc];
        pz[d] = gb[d * 32 + HID + jc];
        pn[d] = gb[d * 32 + 2 * HID + jc];
    }

    float h = 0.0f;
    float hs[HID];
#pragma unroll
    for (int k = 0; k < HID; k++) hs[k] = 0.0f;

#define BCAST(K) hs[K] = __int_as_float(                                     \
        __builtin_amdgcn_ds_swizzle(hh, (K) << 5))   /* src lane = K (32-half) */

    for (int tt = 0; tt < SEQ; tt += PFD) {
#pragma unroll
        for (int d = 0; d < PFD; d++) {
            const float ir = pr[d], iz = pz[d], in_ = pn[d];

            int tn = tt + d + PFD;
            if (tn >= SEQ) tn = SEQ - 1;
            const float* __restrict__ gp = gb + (size_t)tn * 32;
            pr[d] = gp[jc];
            pz[d] = gp[HID + jc];
            pn[d] = gp[2 * HID + jc];

            // 3-accumulator dots: serial chain 4 FMAs (4+3+3 split)
            float ar0 = ir, ar1 = 0.0f, ar2 = 0.0f;
            float az0 = iz, az1 = 0.0f, az2 = 0.0f;
            float an0 = bn, an1 = 0.0f, an2 = 0.0f;
#pragma unroll
            for (int k = 0; k < 4; k++) {
                ar0 = fmaf(wr[k], hs[k], ar0);
                az0 = fmaf(wz[k], hs[k], az0);
                an0 = fmaf(wn[k], hs[k], an0);
            }
#pragma unroll
            for (int k = 4; k < 7; k++) {
                ar1 = fmaf(wr[k], hs[k], ar1);
                az1 = fmaf(wz[k], hs[k], az1);
                an1 = fmaf(wn[k], hs[k], an1);
                ar2 = fmaf(wr[k + 3], hs[k + 3], ar2);
                az2 = fmaf(wz[k + 3], hs[k + 3], az2);
                an2 = fmaf(wn[k + 3], hs[k + 3], an2);
            }
            const float er = __builtin_amdgcn_exp2f((ar0 + ar1) + ar2);
            const float r  = __builtin_amdgcn_rcpf(1.0f + er);
            const float ez = __builtin_amdgcn_exp2f((az0 + az1) + az2);
            const float z  = __builtin_amdgcn_rcpf(1.0f + ez);
            const float en = __builtin_amdgcn_exp2f(fmaf(r, (an0 + an1) + an2, in_));
            const float n  = fmaf(-2.0f, __builtin_amdgcn_rcpf(1.0f + en), 1.0f);
            h = fmaf(z, h - n, n);                 // (1-z)*n + z*h

            const int hh = __float_as_int(h);
            BCAST(0); BCAST(1); BCAST(2); BCAST(3); BCAST(4);
            BCAST(5); BCAST(6); BCAST(7); BCAST(8); BCAST(9);
        }
    }
#undef BCAST

    const float p = fmaf(w_lin[jc], h, w_lin[HID + jc] * hbv);
    float s = 0.0f;
#pragma unroll
    for (int k = 0; k < HID; k++) s += rdlane(p, k);
    if (j == 0) out[b] = s + b_lin[0];
}

// ---------------------------------------------------------------------------
extern "C" void kernel_launch(void* const* d_in, const int* in_sizes, int n_in,
                              void* d_out, int out_size, void* d_ws, size_t ws_size,
                              hipStream_t stream) {
    const float* x      = (const float*)d_in[0];
    const float* w_ih_f = (const float*)d_in[1];
    const float* w_hh_f = (const float*)d_in[2];
    const float* b_ih_f = (const float*)d_in[3];
    const float* b_hh_f = (const float*)d_in[4];
    const float* w_ih_b = (const float*)d_in[5];
    const float* w_hh_b = (const float*)d_in[6];   // unused: backward is one step, h0=0
    const float* b_ih_b = (const float*)d_in[7];
    const float* b_hh_b = (const float*)d_in[8];
    const float* w_lin  = (const float*)d_in[9];
    const float* b_lin  = (const float*)d_in[10];
    float* out = (float*)d_out;

    float* gi = (float*)d_ws;                          // [ROWS][32] = 16.78 MB
    (void)w_hh_b; (void)in_sizes; (void)n_in; (void)out_size; (void)ws_size;

    k_gi  <<<ROWS / 64, 256, 0, stream>>>(x, w_ih_f, b_ih_f, b_hh_f, gi);
    k_scan<<<BATCH, 256, 0, stream>>>(gi, w_hh_f, b_hh_f, x,
                                      w_ih_b, b_ih_b, b_hh_b, w_lin, b_lin, out);
}

// Round 6
// 266.493 us; speedup vs baseline: 1.2675x; 1.2675x over previous
//
#include <hip/hip_runtime.h>

#define EMB 300
#define HID 10
#define BATCH 256
#define SEQ 512
#define G3 30                // 3*HID gates
#define GP 33                // gs row stride (floats) — breaks bank alignment
#define NCH 32               // chunks of 16 rows
#define PFD 4                // scan prefetch depth

#define NLOG2E 1.4426950408889634f   // log2(e)
#define TLOG2E 2.8853900817779268f   // 2*log2(e)

typedef __attribute__((ext_vector_type(8))) short short8;   // 8 bf16
typedef __attribute__((ext_vector_type(4))) float f32x4;    // MFMA C/D

__device__ __forceinline__ float fsig(float x) {
    float e = __builtin_amdgcn_exp2f(-NLOG2E * x);
    return __builtin_amdgcn_rcpf(1.0f + e);
}
__device__ __forceinline__ float ftanh(float x) {
    float e = __builtin_amdgcn_exp2f(TLOG2E * x);
    return fmaf(-2.0f, __builtin_amdgcn_rcpf(1.0f + e), 1.0f);
}
__device__ __forceinline__ float rdlane(float v, int lane) {
    return __int_as_float(__builtin_amdgcn_readlane(__float_as_int(v), lane));
}
__device__ __forceinline__ short bf16_hi(float f) {
    return (short)(__float_as_uint(f) >> 16);
}
__device__ __forceinline__ float bf16_tof(short h) {
    return __uint_as_float(((unsigned)(unsigned short)h) << 16);
}

#define K0T(kt) (((kt) < 9) ? (kt) * 32 : 268)   // tile k-offset (tile 9 masked)

// ---------------------------------------------------------------------------
// Producer-consumer fused bi-GRU. One block per batch, 4 waves, NO barriers
// after init. Waves 1..3: produce 16-row gi chunks into LDS (r4-verified
// split-bf16 MFMA tile math; x 4-deep reg-prefetch RING — rotated by 2 per
// chunk (10 mod 4), so slots are swapped 0<->2, 1<->3 at each chunk end to
// restore canonical order (the r5 bug: missing swap consumed permuted x
// tiles for every chunk >= 1)). Publish via threadfence + release flag.
// Wave 0: forward scan, acquire-polls chunk flags (1 poll / 16 steps).
// Wave 3 computes the backward single step before its chunks.
// ---------------------------------------------------------------------------
__global__ __launch_bounds__(256) void k_all(
    const float* __restrict__ x,
    const float* __restrict__ w_ih, const float* __restrict__ b_ih,
    const float* __restrict__ b_hh, const float* __restrict__ w_hh,
    const float* __restrict__ w_ih_b, const float* __restrict__ b_ih_b,
    const float* __restrict__ b_hh_b,
    const float* __restrict__ w_lin, const float* __restrict__ b_lin,
    float* __restrict__ out)
{
    __shared__ float gs[SEQ * GP];     // 67.6 KB: this batch's gi
    __shared__ float gsum[G3];
    __shared__ float hbs[HID];
    __shared__ int   flg[NCH];
    __shared__ int   flg_hb;

    const int t = threadIdx.x, wave = t >> 6, lane = t & 63;
    const int b = blockIdx.x;
    const float* __restrict__ xb = x + (size_t)b * SEQ * EMB;

    if (t < NCH) flg[t] = 0;
    if (t == 64) flg_hb = 0;
    __syncthreads();                   // the ONLY barrier (all 256 threads)

    if (wave != 0) {
        // ================= producers (waves 1..3) =================
        const int p = wave - 1;
        const int m = lane & 15, q = lane >> 4;

        if (p == 2) {
            // backward direction: ONE GRU step on x[:,511], h0=0.
            if (lane < G3) {
                const float* __restrict__ wrow = w_ih_b + (size_t)lane * EMB;
                const float* __restrict__ xrow = xb + (size_t)(SEQ - 1) * EMB;
                float a0 = 0.f, a1 = 0.f, a2 = 0.f, a3 = 0.f;
                for (int i = 0; i < 75; ++i) {
                    const float4 wv = *(const float4*)(wrow + i * 4);
                    const float4 xv = *(const float4*)(xrow + i * 4);
                    a0 = fmaf(xv.x, wv.x, a0);
                    a1 = fmaf(xv.y, wv.y, a1);
                    a2 = fmaf(xv.z, wv.z, a2);
                    a3 = fmaf(xv.w, wv.w, a3);
                }
                gsum[lane] = ((a0 + a1) + (a2 + a3)) + b_ih_b[lane];
            }
            __threadfence_block();     // wave-level lgkm drain: gsum visible
            if (lane < HID) {
                const float r = fsig(gsum[lane] + b_hh_b[lane]);
                const float z = fsig(gsum[HID + lane] + b_hh_b[HID + lane]);
                const float n = ftanh(fmaf(r, b_hh_b[2 * HID + lane],
                                           gsum[2 * HID + lane]));
                hbs[lane] = (1.0f - z) * n;
            }
            __threadfence_block();
            if (lane == 0)
                __hip_atomic_store(&flg_hb, 1, __ATOMIC_RELEASE,
                                   __HIP_MEMORY_SCOPE_WORKGROUP);
        }

        // gates 0..15 (all r/z): fold b_hh; 20..29 (n): keep b_hh separate.
        const int g1 = 16 + m;
        const int g1c = (g1 < G3) ? g1 : G3 - 1;   // rows 30/31: clamped, unread
        const float bias0 = b_ih[m] + b_hh[m];
        const float bias1 = (g1 < G3) ? (b_ih[g1] + ((g1 < 20) ? b_hh[g1] : 0.0f))
                                      : 0.0f;
        const float sc0 = -NLOG2E;                    // cols 0..15: r/z
        const float sc1 = (m < 4) ? -NLOG2E : TLOG2E; // 16..19 z, 20..29 n
        const float* __restrict__ w0 = w_ih + (size_t)m * EMB;
        const float* __restrict__ w1 = w_ih + (size_t)g1c * EMB;
        const int nI = (p == 2) ? 10 : 11;            // chunks p, p+3, ...

        const float* xr = xb + (size_t)(p * 16 + m) * EMB + q * 8;
        // prime 4-deep x prefetch: tiles 0..3 of first chunk
        float4 s0a = *(const float4*)(xr + K0T(0)), s0b = *(const float4*)(xr + K0T(0) + 4);
        float4 s1a = *(const float4*)(xr + K0T(1)), s1b = *(const float4*)(xr + K0T(1) + 4);
        float4 s2a = *(const float4*)(xr + K0T(2)), s2b = *(const float4*)(xr + K0T(2) + 4);
        float4 s3a = *(const float4*)(xr + K0T(3)), s3b = *(const float4*)(xr + K0T(3) + 4);

        for (int i = 0; i < nI; ++i) {
            const int c = p + 3 * i;
            const float* xn = (i + 1 < nI) ? (xr + (size_t)48 * EMB) : xr;
            f32x4 acc0 = {bias0, bias0, bias0, bias0};
            f32x4 acc1 = {bias1, bias1, bias1, bias1};
#pragma unroll
            for (int kt = 0; kt < 10; ++kt) {
                float4 xa, xc;                        // consume slot kt&3
                if ((kt & 3) == 0)      { xa = s0a; xc = s0b; }
                else if ((kt & 3) == 1) { xa = s1a; xc = s1b; }
                else if ((kt & 3) == 2) { xa = s2a; xc = s2b; }
                else                    { xa = s3a; xc = s3b; }
                {                                     // refill with tile kt+4
                    const float* src = (kt + 4 < 10) ? xr : xn;
                    const int kk = (kt + 4 < 10) ? K0T(kt + 4) : K0T(kt - 6);
                    const float4 na = *(const float4*)(src + kk);
                    const float4 nb = *(const float4*)(src + kk + 4);
                    if ((kt & 3) == 0)      { s0a = na; s0b = nb; }
                    else if ((kt & 3) == 1) { s1a = na; s1b = nb; }
                    else if ((kt & 3) == 2) { s2a = na; s2b = nb; }
                    else                    { s3a = na; s3b = nb; }
                }
                const int kb = K0T(kt) + q * 8;       // weights: L1-hot direct
                const float4 wa0 = *(const float4*)(w0 + kb);
                const float4 wb0 = *(const float4*)(w0 + kb + 4);
                const float4 wa1 = *(const float4*)(w1 + kb);
                const float4 wb1 = *(const float4*)(w1 + kb + 4);

                float av[8] = {xa.x, xa.y, xa.z, xa.w, xc.x, xc.y, xc.z, xc.w};
                if (kt == 9) {                        // tile9: ki<20 in tile 8
#pragma unroll
                    for (int jj = 0; jj < 8; jj++)
                        if (q * 8 + jj < 20) av[jj] = 0.0f;
                }
                float wv0[8] = {wa0.x, wa0.y, wa0.z, wa0.w, wb0.x, wb0.y, wb0.z, wb0.w};
                float wv1[8] = {wa1.x, wa1.y, wa1.z, wa1.w, wb1.x, wb1.y, wb1.z, wb1.w};

                short8 ah, al, bh0, bl0, bh1, bl1;
#pragma unroll
                for (int jj = 0; jj < 8; jj++) {
                    short hi;
                    hi = bf16_hi(av[jj]);  ah[jj] = hi;  al[jj]  = bf16_hi(av[jj]  - bf16_tof(hi));
                    hi = bf16_hi(wv0[jj]); bh0[jj] = hi; bl0[jj] = bf16_hi(wv0[jj] - bf16_tof(hi));
                    hi = bf16_hi(wv1[jj]); bh1[jj] = hi; bl1[jj] = bf16_hi(wv1[jj] - bf16_tof(hi));
                }
                acc0 = __builtin_amdgcn_mfma_f32_16x16x32_bf16(ah, bh0, acc0, 0, 0, 0);
                acc0 = __builtin_amdgcn_mfma_f32_16x16x32_bf16(al, bh0, acc0, 0, 0, 0);
                acc0 = __builtin_amdgcn_mfma_f32_16x16x32_bf16(ah, bl0, acc0, 0, 0, 0);
                acc1 = __builtin_amdgcn_mfma_f32_16x16x32_bf16(ah, bh1, acc1, 0, 0, 0);
                acc1 = __builtin_amdgcn_mfma_f32_16x16x32_bf16(al, bh1, acc1, 0, 0, 0);
                acc1 = __builtin_amdgcn_mfma_f32_16x16x32_bf16(ah, bl1, acc1, 0, 0, 0);
            }
#pragma unroll
            for (int r = 0; r < 4; ++r) {             // epilogue: scale + LDS
                const int row = c * 16 + q * 4 + r;
                gs[row * GP + m]      = acc0[r] * sc0;
                gs[row * GP + 16 + m] = acc1[r] * sc1;
            }
            __threadfence_block();                    // all lanes' ds_writes done
            if (lane == 0)
                __hip_atomic_store(&flg[c], 1, __ATOMIC_RELEASE,
                                   __HIP_MEMORY_SCOPE_WORKGROUP);

            // ring rotated by 10 mod 4 = 2 during this chunk: restore
            // canonical slot order (THE r5 FIX — slots held t2',t3',t0',t1')
            {
                float4 tmp;
                tmp = s0a; s0a = s2a; s2a = tmp;
                tmp = s0b; s0b = s2b; s2b = tmp;
                tmp = s1a; s1a = s3a; s3a = tmp;
                tmp = s1b; s1b = s3b; s3b = tmp;
            }
            xr = xn;
        }
        return;
    }

    // ===================== scanner (wave 0) =====================
    const int j = lane;
    const int jc = (j < HID) ? j : HID - 1;

    float wr[HID], wz[HID], wn[HID];
#pragma unroll
    for (int k = 0; k < HID; k++) {
        wr[k] = -NLOG2E * w_hh[jc * HID + k];
        wz[k] = -NLOG2E * w_hh[(HID + jc) * HID + k];
        wn[k] =  TLOG2E * w_hh[(2 * HID + jc) * HID + k];
    }
    const float bn  = TLOG2E * b_hh[2 * HID + jc];   // r/z b_hh folded into gi
    const float wl0 = w_lin[jc], wl1 = w_lin[HID + jc];

    while (__hip_atomic_load(&flg[0], __ATOMIC_ACQUIRE,
                             __HIP_MEMORY_SCOPE_WORKGROUP) == 0)
        __builtin_amdgcn_s_sleep(1);

    float pr[PFD], pz[PFD], pn[PFD];
#pragma unroll
    for (int d = 0; d < PFD; d++) {
        pr[d] = gs[d * GP + jc];
        pz[d] = gs[d * GP + HID + jc];
        pn[d] = gs[d * GP + 2 * HID + jc];
    }

    float h = 0.0f;
    float hs[HID];
#pragma unroll
    for (int k = 0; k < HID; k++) hs[k] = 0.0f;

    for (int c = 0; c < NCH; ++c) {
        // chunk c was awaited last iter; prefetch reaches into c+1 -> wait it
        if (c + 1 < NCH)
            while (__hip_atomic_load(&flg[c + 1], __ATOMIC_ACQUIRE,
                                     __HIP_MEMORY_SCOPE_WORKGROUP) == 0)
                __builtin_amdgcn_s_sleep(1);
        for (int tt = c * 16; tt < c * 16 + 16; tt += PFD) {
#pragma unroll
            for (int d = 0; d < PFD; d++) {
                const float ir = pr[d], iz = pz[d], in_ = pn[d];

                int tn = tt + d + PFD;
                if (tn >= SEQ) tn = SEQ - 1;
                const float* __restrict__ gp = gs + tn * GP;
                pr[d] = gp[jc];
                pz[d] = gp[HID + jc];
                pn[d] = gp[2 * HID + jc];

                // 3-accumulator dots: serial chain 4 FMAs (4+3+3)
                float ar0 = ir, ar1 = 0.f, ar2 = 0.f;
                float az0 = iz, az1 = 0.f, az2 = 0.f;
                float an0 = bn, an1 = 0.f, an2 = 0.f;
#pragma unroll
                for (int k = 0; k < 4; k++) {
                    ar0 = fmaf(wr[k], hs[k], ar0);
                    az0 = fmaf(wz[k], hs[k], az0);
                    an0 = fmaf(wn[k], hs[k], an0);
                }
#pragma unroll
                for (int k = 4; k < 7; k++) {
                    ar1 = fmaf(wr[k], hs[k], ar1);
                    az1 = fmaf(wz[k], hs[k], az1);
                    an1 = fmaf(wn[k], hs[k], an1);
                    ar2 = fmaf(wr[k + 3], hs[k + 3], ar2);
                    az2 = fmaf(wz[k + 3], hs[k + 3], az2);
                    an2 = fmaf(wn[k + 3], hs[k + 3], an2);
                }
                const float er = __builtin_amdgcn_exp2f((ar0 + ar1) + ar2);
                const float r  = __builtin_amdgcn_rcpf(1.0f + er);
                const float ez = __builtin_amdgcn_exp2f((az0 + az1) + az2);
                const float z  = __builtin_amdgcn_rcpf(1.0f + ez);
                const float en = __builtin_amdgcn_exp2f(fmaf(r, (an0 + an1) + an2, in_));
                const float n  = fmaf(-2.0f, __builtin_amdgcn_rcpf(1.0f + en), 1.0f);
                h = fmaf(z, h - n, n);                 // (1-z)*n + z*h

                hs[0] = rdlane(h, 0); hs[1] = rdlane(h, 1);
                hs[2] = rdlane(h, 2); hs[3] = rdlane(h, 3);
                hs[4] = rdlane(h, 4); hs[5] = rdlane(h, 5);
                hs[6] = rdlane(h, 6); hs[7] = rdlane(h, 7);
                hs[8] = rdlane(h, 8); hs[9] = rdlane(h, 9);
            }
        }
    }

    while (__hip_atomic_load(&flg_hb, __ATOMIC_ACQUIRE,
                             __HIP_MEMORY_SCOPE_WORKGROUP) == 0)
        __builtin_amdgcn_s_sleep(1);
    const float hbv = hbs[jc];
    const float pfin = fmaf(wl0, h, wl1 * hbv);
    float s = 0.0f;
#pragma unroll
    for (int k = 0; k < HID; k++) s += rdlane(pfin, k);
    if (j == 0) out[b] = s + b_lin[0];
}

// ---------------------------------------------------------------------------
extern "C" void kernel_launch(void* const* d_in, const int* in_sizes, int n_in,
                              void* d_out, int out_size, void* d_ws, size_t ws_size,
                              hipStream_t stream) {
    const float* x      = (const float*)d_in[0];
    const float* w_ih_f = (const float*)d_in[1];
    const float* w_hh_f = (const float*)d_in[2];
    const float* b_ih_f = (const float*)d_in[3];
    const float* b_hh_f = (const float*)d_in[4];
    const float* w_ih_b = (const float*)d_in[5];
    const float* w_hh_b = (const float*)d_in[6];   // unused: backward is one step, h0=0
    const float* b_ih_b = (const float*)d_in[7];
    const float* b_hh_b = (const float*)d_in[8];
    const float* w_lin  = (const float*)d_in[9];
    const float* b_lin  = (const float*)d_in[10];
    (void)w_hh_b; (void)in_sizes; (void)n_in; (void)out_size;
    (void)d_ws; (void)ws_size;                     // workspace unused

    k_all<<<BATCH, 256, 0, stream>>>(x, w_ih_f, b_ih_f, b_hh_f, w_hh_f,
                                     w_ih_b, b_ih_b, b_hh_b, w_lin, b_lin,
                                     (float*)d_out);
}

// Round 7
// 262.902 us; speedup vs baseline: 1.2848x; 1.0137x over previous
//
#include <hip/hip_runtime.h>

#define EMB 300
#define HID 10
#define BATCH 256
#define SEQ 512
#define G3 30                // 3*HID gates
#define GP 33                // gs row stride (floats) — breaks bank alignment
#define NCH 32               // chunks of 16 rows

#define NLOG2E 1.4426950408889634f   // log2(e)
#define TLOG2E 2.8853900817779268f   // 2*log2(e)

typedef __attribute__((ext_vector_type(8))) short short8;   // 8 bf16
typedef __attribute__((ext_vector_type(4))) float f32x4;    // MFMA C/D

__device__ __forceinline__ float fsig(float x) {
    float e = __builtin_amdgcn_exp2f(-NLOG2E * x);
    return __builtin_amdgcn_rcpf(1.0f + e);
}
__device__ __forceinline__ float ftanh(float x) {
    float e = __builtin_amdgcn_exp2f(TLOG2E * x);
    return fmaf(-2.0f, __builtin_amdgcn_rcpf(1.0f + e), 1.0f);
}
__device__ __forceinline__ float rdlane(float v, int lane) {
    return __int_as_float(__builtin_amdgcn_readlane(__float_as_int(v), lane));
}
__device__ __forceinline__ short bf16_hi(float f) {
    return (short)(__float_as_uint(f) >> 16);
}
__device__ __forceinline__ float bf16_tof(short h) {
    return __uint_as_float(((unsigned)(unsigned short)h) << 16);
}

#define K0T(kt) (((kt) < 9) ? (kt) * 32 : 268)   // tile k-offset (tile 9 masked)

// ---------------------------------------------------------------------------
// Producer-consumer fused bi-GRU (r6-verified structure). One block per
// batch, 4 waves, no barriers after init. Waves 1..3: produce 16-row gi
// chunks into LDS (split-bf16 MFMA; x 4-deep reg-prefetch ring with the
// 0<->2 1<->3 end-of-chunk swap), publish via fence + release flag. Wave 0
// scans. v7 scanner: per-chunk hoist of all 48 ds_reads (compile-time
// indices, no tn clamp, no per-step address math) + ds_bpermute broadcast
// (pipelined LDS pipe, no VALU->SGPR hazard s_nops).
// ---------------------------------------------------------------------------
__global__ __launch_bounds__(256) void k_all(
    const float* __restrict__ x,
    const float* __restrict__ w_ih, const float* __restrict__ b_ih,
    const float* __restrict__ b_hh, const float* __restrict__ w_hh,
    const float* __restrict__ w_ih_b, const float* __restrict__ b_ih_b,
    const float* __restrict__ b_hh_b,
    const float* __restrict__ w_lin, const float* __restrict__ b_lin,
    float* __restrict__ out)
{
    __shared__ float gs[SEQ * GP];     // 67.6 KB: this batch's gi
    __shared__ float gsum[G3];
    __shared__ float hbs[HID];
    __shared__ int   flg[NCH];
    __shared__ int   flg_hb;

    const int t = threadIdx.x, wave = t >> 6, lane = t & 63;
    const int b = blockIdx.x;
    const float* __restrict__ xb = x + (size_t)b * SEQ * EMB;

    if (t < NCH) flg[t] = 0;
    if (t == 64) flg_hb = 0;
    __syncthreads();                   // the ONLY barrier (all 256 threads)

    if (wave != 0) {
        // ================= producers (waves 1..3) — r6 verbatim =================
        const int p = wave - 1;
        const int m = lane & 15, q = lane >> 4;

        if (p == 2) {
            // backward direction: ONE GRU step on x[:,511], h0=0.
            if (lane < G3) {
                const float* __restrict__ wrow = w_ih_b + (size_t)lane * EMB;
                const float* __restrict__ xrow = xb + (size_t)(SEQ - 1) * EMB;
                float a0 = 0.f, a1 = 0.f, a2 = 0.f, a3 = 0.f;
                for (int i = 0; i < 75; ++i) {
                    const float4 wv = *(const float4*)(wrow + i * 4);
                    const float4 xv = *(const float4*)(xrow + i * 4);
                    a0 = fmaf(xv.x, wv.x, a0);
                    a1 = fmaf(xv.y, wv.y, a1);
                    a2 = fmaf(xv.z, wv.z, a2);
                    a3 = fmaf(xv.w, wv.w, a3);
                }
                gsum[lane] = ((a0 + a1) + (a2 + a3)) + b_ih_b[lane];
            }
            __threadfence_block();
            if (lane < HID) {
                const float r = fsig(gsum[lane] + b_hh_b[lane]);
                const float z = fsig(gsum[HID + lane] + b_hh_b[HID + lane]);
                const float n = ftanh(fmaf(r, b_hh_b[2 * HID + lane],
                                           gsum[2 * HID + lane]));
                hbs[lane] = (1.0f - z) * n;
            }
            __threadfence_block();
            if (lane == 0)
                __hip_atomic_store(&flg_hb, 1, __ATOMIC_RELEASE,
                                   __HIP_MEMORY_SCOPE_WORKGROUP);
        }

        const int g1 = 16 + m;
        const int g1c = (g1 < G3) ? g1 : G3 - 1;   // rows 30/31: clamped, unread
        const float bias0 = b_ih[m] + b_hh[m];
        const float bias1 = (g1 < G3) ? (b_ih[g1] + ((g1 < 20) ? b_hh[g1] : 0.0f))
                                      : 0.0f;
        const float sc0 = -NLOG2E;                    // cols 0..15: r/z
        const float sc1 = (m < 4) ? -NLOG2E : TLOG2E; // 16..19 z, 20..29 n
        const float* __restrict__ w0 = w_ih + (size_t)m * EMB;
        const float* __restrict__ w1 = w_ih + (size_t)g1c * EMB;
        const int nI = (p == 2) ? 10 : 11;            // chunks p, p+3, ...

        const float* xr = xb + (size_t)(p * 16 + m) * EMB + q * 8;
        float4 s0a = *(const float4*)(xr + K0T(0)), s0b = *(const float4*)(xr + K0T(0) + 4);
        float4 s1a = *(const float4*)(xr + K0T(1)), s1b = *(const float4*)(xr + K0T(1) + 4);
        float4 s2a = *(const float4*)(xr + K0T(2)), s2b = *(const float4*)(xr + K0T(2) + 4);
        float4 s3a = *(const float4*)(xr + K0T(3)), s3b = *(const float4*)(xr + K0T(3) + 4);

        for (int i = 0; i < nI; ++i) {
            const int c = p + 3 * i;
            const float* xn = (i + 1 < nI) ? (xr + (size_t)48 * EMB) : xr;
            f32x4 acc0 = {bias0, bias0, bias0, bias0};
            f32x4 acc1 = {bias1, bias1, bias1, bias1};
#pragma unroll
            for (int kt = 0; kt < 10; ++kt) {
                float4 xa, xc;                        // consume slot kt&3
                if ((kt & 3) == 0)      { xa = s0a; xc = s0b; }
                else if ((kt & 3) == 1) { xa = s1a; xc = s1b; }
                else if ((kt & 3) == 2) { xa = s2a; xc = s2b; }
                else                    { xa = s3a; xc = s3b; }
                {                                     // refill with tile kt+4
                    const float* src = (kt + 4 < 10) ? xr : xn;
                    const int kk = (kt + 4 < 10) ? K0T(kt + 4) : K0T(kt - 6);
                    const float4 na = *(const float4*)(src + kk);
                    const float4 nb = *(const float4*)(src + kk + 4);
                    if ((kt & 3) == 0)      { s0a = na; s0b = nb; }
                    else if ((kt & 3) == 1) { s1a = na; s1b = nb; }
                    else if ((kt & 3) == 2) { s2a = na; s2b = nb; }
                    else                    { s3a = na; s3b = nb; }
                }
                const int kb = K0T(kt) + q * 8;       // weights: L1-hot direct
                const float4 wa0 = *(const float4*)(w0 + kb);
                const float4 wb0 = *(const float4*)(w0 + kb + 4);
                const float4 wa1 = *(const float4*)(w1 + kb);
                const float4 wb1 = *(const float4*)(w1 + kb + 4);

                float av[8] = {xa.x, xa.y, xa.z, xa.w, xc.x, xc.y, xc.z, xc.w};
                if (kt == 9) {                        // tile9: ki<20 in tile 8
#pragma unroll
                    for (int jj = 0; jj < 8; jj++)
                        if (q * 8 + jj < 20) av[jj] = 0.0f;
                }
                float wv0[8] = {wa0.x, wa0.y, wa0.z, wa0.w, wb0.x, wb0.y, wb0.z, wb0.w};
                float wv1[8] = {wa1.x, wa1.y, wa1.z, wa1.w, wb1.x, wb1.y, wb1.z, wb1.w};

                short8 ah, al, bh0, bl0, bh1, bl1;
#pragma unroll
                for (int jj = 0; jj < 8; jj++) {
                    short hi;
                    hi = bf16_hi(av[jj]);  ah[jj] = hi;  al[jj]  = bf16_hi(av[jj]  - bf16_tof(hi));
                    hi = bf16_hi(wv0[jj]); bh0[jj] = hi; bl0[jj] = bf16_hi(wv0[jj] - bf16_tof(hi));
                    hi = bf16_hi(wv1[jj]); bh1[jj] = hi; bl1[jj] = bf16_hi(wv1[jj] - bf16_tof(hi));
                }
                acc0 = __builtin_amdgcn_mfma_f32_16x16x32_bf16(ah, bh0, acc0, 0, 0, 0);
                acc0 = __builtin_amdgcn_mfma_f32_16x16x32_bf16(al, bh0, acc0, 0, 0, 0);
                acc0 = __builtin_amdgcn_mfma_f32_16x16x32_bf16(ah, bl0, acc0, 0, 0, 0);
                acc1 = __builtin_amdgcn_mfma_f32_16x16x32_bf16(ah, bh1, acc1, 0, 0, 0);
                acc1 = __builtin_amdgcn_mfma_f32_16x16x32_bf16(al, bh1, acc1, 0, 0, 0);
                acc1 = __builtin_amdgcn_mfma_f32_16x16x32_bf16(ah, bl1, acc1, 0, 0, 0);
            }
#pragma unroll
            for (int r = 0; r < 4; ++r) {             // epilogue: scale + LDS
                const int row = c * 16 + q * 4 + r;
                gs[row * GP + m]      = acc0[r] * sc0;
                gs[row * GP + 16 + m] = acc1[r] * sc1;
            }
            __threadfence_block();
            if (lane == 0)
                __hip_atomic_store(&flg[c], 1, __ATOMIC_RELEASE,
                                   __HIP_MEMORY_SCOPE_WORKGROUP);

            {   // ring rotated by 10 mod 4 = 2: restore canonical slot order
                float4 tmp;
                tmp = s0a; s0a = s2a; s2a = tmp;
                tmp = s0b; s0b = s2b; s2b = tmp;
                tmp = s1a; s1a = s3a; s3a = tmp;
                tmp = s1b; s1b = s3b; s3b = tmp;
            }
            xr = xn;
        }
        return;
    }

    // ===================== scanner (wave 0), v7 =====================
    const int j = lane;
    const int jc = (j < HID) ? j : HID - 1;

    float wr[HID], wz[HID], wn[HID];
#pragma unroll
    for (int k = 0; k < HID; k++) {
        wr[k] = -NLOG2E * w_hh[jc * HID + k];
        wz[k] = -NLOG2E * w_hh[(HID + jc) * HID + k];
        wn[k] =  TLOG2E * w_hh[(2 * HID + jc) * HID + k];
    }
    const float bn  = TLOG2E * b_hh[2 * HID + jc];   // r/z b_hh folded into gi
    const float wl0 = w_lin[jc], wl1 = w_lin[HID + jc];

    float h = 0.0f;
    float hs[HID];
#pragma unroll
    for (int k = 0; k < HID; k++) hs[k] = 0.0f;

    // broadcast h[K] (lane K) to all lanes via LDS crossbar — pipelined,
    // no VALU->SGPR hazard s_nops (vs readlane)
#define BC(K) hs[K] = __int_as_float(__builtin_amdgcn_ds_bpermute((K) << 2, hh))

    for (int c = 0; c < NCH; ++c) {
        while (__hip_atomic_load(&flg[c], __ATOMIC_ACQUIRE,
                                 __HIP_MEMORY_SCOPE_WORKGROUP) == 0)
            __builtin_amdgcn_s_sleep(1);

        // hoist the whole chunk's gate inputs: 48 ds_reads, compile-time
        // indices (c*16+s <= 511 always — no clamp, no per-step addressing)
        float pr[16], pz[16], pn[16];
#pragma unroll
        for (int s = 0; s < 16; ++s) {
            const float* __restrict__ gp = gs + (c * 16 + s) * GP;
            pr[s] = gp[jc];
            pz[s] = gp[HID + jc];
            pn[s] = gp[2 * HID + jc];
        }

#pragma unroll
        for (int s = 0; s < 16; ++s) {
            // 3-accumulator dots: serial chain 4 FMAs (4+3+3)
            float ar0 = pr[s], ar1 = 0.f, ar2 = 0.f;
            float az0 = pz[s], az1 = 0.f, az2 = 0.f;
            float an0 = bn,    an1 = 0.f, an2 = 0.f;
#pragma unroll
            for (int k = 0; k < 4; k++) {
                ar0 = fmaf(wr[k], hs[k], ar0);
                az0 = fmaf(wz[k], hs[k], az0);
                an0 = fmaf(wn[k], hs[k], an0);
            }
#pragma unroll
            for (int k = 4; k < 7; k++) {
                ar1 = fmaf(wr[k], hs[k], ar1);
                az1 = fmaf(wz[k], hs[k], az1);
                an1 = fmaf(wn[k], hs[k], an1);
                ar2 = fmaf(wr[k + 3], hs[k + 3], ar2);
                az2 = fmaf(wz[k + 3], hs[k + 3], az2);
                an2 = fmaf(wn[k + 3], hs[k + 3], an2);
            }
            const float er = __builtin_amdgcn_exp2f((ar0 + ar1) + ar2);
            const float r  = __builtin_amdgcn_rcpf(1.0f + er);
            const float ez = __builtin_amdgcn_exp2f((az0 + az1) + az2);
            const float z  = __builtin_amdgcn_rcpf(1.0f + ez);
            const float en = __builtin_amdgcn_exp2f(fmaf(r, (an0 + an1) + an2, pn[s]));
            const float n  = fmaf(-2.0f, __builtin_amdgcn_rcpf(1.0f + en), 1.0f);
            h = fmaf(z, h - n, n);                 // (1-z)*n + z*h

            const int hh = __float_as_int(h);
            BC(0); BC(1); BC(2); BC(3); BC(4);
            BC(5); BC(6); BC(7); BC(8); BC(9);
        }
    }
#undef BC

    while (__hip_atomic_load(&flg_hb, __ATOMIC_ACQUIRE,
                             __HIP_MEMORY_SCOPE_WORKGROUP) == 0)
        __builtin_amdgcn_s_sleep(1);
    const float hbv = hbs[jc];
    const float pfin = fmaf(wl0, h, wl1 * hbv);
    float s = 0.0f;
#pragma unroll
    for (int k = 0; k < HID; k++) s += rdlane(pfin, k);
    if (j == 0) out[b] = s + b_lin[0];
}

// ---------------------------------------------------------------------------
extern "C" void kernel_launch(void* const* d_in, const int* in_sizes, int n_in,
                              void* d_out, int out_size, void* d_ws, size_t ws_size,
                              hipStream_t stream) {
    const float* x      = (const float*)d_in[0];
    const float* w_ih_f = (const float*)d_in[1];
    const float* w_hh_f = (const float*)d_in[2];
    const float* b_ih_f = (const float*)d_in[3];
    const float* b_hh_f = (const float*)d_in[4];
    const float* w_ih_b = (const float*)d_in[5];
    const float* w_hh_b = (const float*)d_in[6];   // unused: backward is one step, h0=0
    const float* b_ih_b = (const float*)d_in[7];
    const float* b_hh_b = (const float*)d_in[8];
    const float* w_lin  = (const float*)d_in[9];
    const float* b_lin  = (const float*)d_in[10];
    (void)w_hh_b; (void)in_sizes; (void)n_in; (void)out_size;
    (void)d_ws; (void)ws_size;                     // workspace unused

    k_all<<<BATCH, 256, 0, stream>>>(x, w_ih_f, b_ih_f, b_hh_f, w_hh_f,
                                     w_ih_b, b_ih_b, b_hh_b, w_lin, b_lin,
                                     (float*)d_out);
}